// Round 2
// baseline (136.887 us; speedup 1.0000x reference)
//
#include <hip/hip_runtime.h>

typedef float f32x4 __attribute__((ext_vector_type(4)));
typedef __bf16 bf16x8 __attribute__((ext_vector_type(8)));
typedef unsigned short u16x8 __attribute__((ext_vector_type(8)));
typedef unsigned short u16x4 __attribute__((ext_vector_type(4)));

__device__ __forceinline__ unsigned short f2bf(float f) {
  union { float f; unsigned u; } v; v.f = f;
  unsigned r = v.u + 0x7FFFu + ((v.u >> 16) & 1u);
  return (unsigned short)(r >> 16);
}

__device__ __forceinline__ float min3f(float a, float b, float c) {
  return fminf(fminf(a, b), c);
}
__device__ __forceinline__ float max3f(float a, float b, float c) {
  return fmaxf(fmaxf(a, b), c);
}

// Exact 13-op median-of-9 (verified via 0/1 principle for monotone networks):
// med3( max3(row mins), med3(row medians), min3(row maxes) )
__device__ __forceinline__ float median9(float p0, float p1, float p2,
                                         float p3, float p4, float p5,
                                         float p6, float p7, float p8) {
  float mn0 = min3f(p0, p1, p2), md0 = __builtin_amdgcn_fmed3f(p0, p1, p2), mx0 = max3f(p0, p1, p2);
  float mn1 = min3f(p3, p4, p5), md1 = __builtin_amdgcn_fmed3f(p3, p4, p5), mx1 = max3f(p3, p4, p5);
  float mn2 = min3f(p6, p7, p8), md2 = __builtin_amdgcn_fmed3f(p6, p7, p8), mx2 = max3f(p6, p7, p8);
  float t0 = max3f(mn0, mn1, mn2);
  float t1 = __builtin_amdgcn_fmed3f(md0, md1, md2);
  float t2 = min3f(mx0, mx1, mx2);
  return __builtin_amdgcn_fmed3f(t0, t1, t2);
}

// conv_w fp32 [256][256] -> bf16 (RNE) in workspace
__global__ void wconv_k(const float* __restrict__ w, unsigned short* __restrict__ wbf) {
  int i = (blockIdx.x * 256 + threadIdx.x) * 4;
  f32x4 v = *(const f32x4*)(w + i);
  u16x4 o;
  o[0] = f2bf(v[0]); o[1] = f2bf(v[1]); o[2] = f2bf(v[2]); o[3] = f2bf(v[3]);
  *(u16x4*)(wbf + i) = o;
}

// One block = one (batch, row): all 256 out-channels x 64 pixels.
// K-loop over input channels in steps of 32.
__launch_bounds__(256, 4)
__global__ void fused_k(const float* __restrict__ x,
                        const unsigned short* __restrict__ wbf,
                        const float* __restrict__ bias,
                        float* __restrict__ out) {
  __shared__ float Xs[32][3][72];          // 27.0 KB: data cols 4..67, zeros at 3 & 68
  __shared__ unsigned short Bt[64][40];    //  5.0 KB: med tile [px][c_local], pad 40
  __shared__ float BiasS[256];

  const int t   = threadIdx.x;
  const int blk = blockIdx.x;
  const int swz = ((blk & 7) << 8) | (blk >> 3);   // XCD-bijective swizzle (2048 = 8*256)
  const int b   = swz >> 6;
  const int r   = swz & 63;
  const int lane = t & 63;
  const int w    = t >> 6;       // wave 0..3
  const int g    = lane >> 4;    // lane group 0..3
  const int l15  = lane & 15;

  BiasS[t] = bias[t];
  if (t < 192) {                 // zero the pad columns (static throughout)
    int ci = t / 6, rem = t - ci * 6;
    int dr = rem >> 1, col = (rem & 1) ? 68 : 3;
    Xs[ci][dr][col] = 0.f;
  }

  const float* xb = x + ((size_t)b << 20);   // b * 256*64*64

  f32x4 acc[4][4];
  #pragma unroll
  for (int m = 0; m < 4; ++m)
    #pragma unroll
    for (int n = 0; n < 4; ++n)
      acc[m][n] = (f32x4){0.f, 0.f, 0.f, 0.f};

  f32x4 xr[6];
  // prologue: load ks=0 x tile into registers
  #pragma unroll
  for (int p = 0; p < 6; ++p) {
    int task = (p << 8) + t, seg = task & 15, rowid = task >> 4;
    int dr = rowid >> 5, ci = rowid & 31, gr = r + dr - 1;
    f32x4 v = (f32x4){0.f, 0.f, 0.f, 0.f};
    if ((unsigned)gr < 64u)
      v = *(const f32x4*)(xb + ((size_t)ci << 12) + (gr << 6) + (seg << 2));
    xr[p] = v;
  }

  for (int ks = 0; ks < 8; ++ks) {
    const int c0 = ks << 5;
    __syncthreads();             // Xs/Bt free from previous step's reads

    // --- commit register-staged x tile to LDS ---
    #pragma unroll
    for (int p = 0; p < 6; ++p) {
      int task = (p << 8) + t, seg = task & 15, rowid = task >> 4;
      int dr = rowid >> 5, ci = rowid & 31;
      *(f32x4*)&Xs[ci][dr][4 + (seg << 2)] = xr[p];
    }

    // --- W fragments straight from global (L2-hot, 128 KB total) ---
    bf16x8 a[4];
    #pragma unroll
    for (int m = 0; m < 4; ++m) {
      int o = (w << 6) + (m << 4) + l15;
      a[m] = __builtin_bit_cast(bf16x8, *(const u16x8*)(wbf + (o << 8) + c0 + (g << 3)));
    }

    __syncthreads();

    // --- medians: px = lane (conflict-free), c = w*8 + i ---
    {
      unsigned short mbuf[8];
      const int base = 4 + lane;
      #pragma unroll
      for (int i = 0; i < 8; ++i) {
        const float* rowp = &Xs[(w << 3) + i][0][0];
        float p0 = rowp[base - 1],       p1 = rowp[base],       p2 = rowp[base + 1];
        float p3 = rowp[72 + base - 1],  p4 = rowp[72 + base],  p5 = rowp[72 + base + 1];
        float p6 = rowp[144 + base - 1], p7 = rowp[144 + base], p8 = rowp[144 + base + 1];
        mbuf[i] = f2bf(median9(p0,p1,p2,p3,p4,p5,p6,p7,p8));
      }
      *(u16x8*)&Bt[lane][w << 3] = *(const u16x8*)mbuf;
    }
    __syncthreads();

    // --- B fragments + prefetch next x tile + MFMA ---
    bf16x8 bb[4];
    #pragma unroll
    for (int n = 0; n < 4; ++n)
      bb[n] = __builtin_bit_cast(bf16x8, *(const u16x8*)&Bt[(n << 4) + l15][g << 3]);

    if (ks < 7) {
      const int c1 = c0 + 32;
      #pragma unroll
      for (int p = 0; p < 6; ++p) {
        int task = (p << 8) + t, seg = task & 15, rowid = task >> 4;
        int dr = rowid >> 5, ci = rowid & 31, gr = r + dr - 1;
        f32x4 v = (f32x4){0.f, 0.f, 0.f, 0.f};
        if ((unsigned)gr < 64u)
          v = *(const f32x4*)(xb + ((size_t)(c1 + ci) << 12) + (gr << 6) + (seg << 2));
        xr[p] = v;
      }
    }

    #pragma unroll
    for (int m = 0; m < 4; ++m)
      #pragma unroll
      for (int n = 0; n < 4; ++n)
        acc[m][n] = __builtin_amdgcn_mfma_f32_16x16x32_bf16(a[m], bb[n], acc[m][n], 0, 0, 0);
  }

  // --- epilogue: out = x + acc + bias ---
  #pragma unroll
  for (int m = 0; m < 4; ++m) {
    const int o = (w << 6) + (m << 4) + (g << 2);
    #pragma unroll
    for (int n = 0; n < 4; ++n) {
      const int px = (n << 4) + l15;
      const size_t base = ((((size_t)b << 8) + (size_t)o) << 12) + ((size_t)r << 6) + (size_t)px;
      #pragma unroll
      for (int q = 0; q < 4; ++q) {
        const size_t idx = base + ((size_t)q << 12);
        out[idx] = x[idx] + acc[m][n][q] + BiasS[o + q];
      }
    }
  }
}

extern "C" void kernel_launch(void* const* d_in, const int* in_sizes, int n_in,
                              void* d_out, int out_size, void* d_ws, size_t ws_size,
                              hipStream_t stream) {
  const float* x  = (const float*)d_in[0];
  const float* cw = (const float*)d_in[1];
  const float* cb = (const float*)d_in[2];
  float* out = (float*)d_out;
  unsigned short* wbf = (unsigned short*)d_ws;   // 128 KB

  hipLaunchKernelGGL(wconv_k, dim3(64), dim3(256), 0, stream, cw, wbf);
  hipLaunchKernelGGL(fused_k, dim3(2048), dim3(256), 0, stream, x, wbf, cb, out);
}

// Round 3
// 110.577 us; speedup vs baseline: 1.2379x; 1.2379x over previous
//
#include <hip/hip_runtime.h>

typedef float f32x4 __attribute__((ext_vector_type(4)));
typedef __bf16 bf16x8 __attribute__((ext_vector_type(8)));
typedef unsigned short u16x8 __attribute__((ext_vector_type(8)));
typedef unsigned short u16x4 __attribute__((ext_vector_type(4)));

__device__ __forceinline__ unsigned short f2bf(float f) {
  union { float f; unsigned u; } v; v.f = f;
  unsigned r = v.u + 0x7FFFu + ((v.u >> 16) & 1u);
  return (unsigned short)(r >> 16);
}

__device__ __forceinline__ float min3f(float a, float b, float c) {
  return fminf(fminf(a, b), c);
}
__device__ __forceinline__ float max3f(float a, float b, float c) {
  return fmaxf(fmaxf(a, b), c);
}
__device__ __forceinline__ float med3f(float a, float b, float c) {
  return __builtin_amdgcn_fmed3f(a, b, c);
}

// conv_w fp32 [256][256] -> bf16 (RNE) in workspace
__global__ void wconv_k(const float* __restrict__ w, unsigned short* __restrict__ wbf) {
  int i = (blockIdx.x * 256 + threadIdx.x) * 4;
  f32x4 v = *(const f32x4*)(w + i);
  u16x4 o;
  o[0] = f2bf(v[0]); o[1] = f2bf(v[1]); o[2] = f2bf(v[2]); o[3] = f2bf(v[3]);
  *(u16x4*)(wbf + i) = o;
}

// Load 10 floats (strip px0-1 .. px0+8) of one image row into d[0..9].
__device__ __forceinline__ void load_row(const float* p, bool valid, bool hasL, bool hasR,
                                         float* d) {
  f32x4 v0 = (f32x4){0.f, 0.f, 0.f, 0.f};
  f32x4 v1 = (f32x4){0.f, 0.f, 0.f, 0.f};
  float l = 0.f, rr = 0.f;
  if (valid) {
    v0 = *(const f32x4*)p;
    v1 = *(const f32x4*)(p + 4);
    if (hasL) l  = p[-1];
    if (hasR) rr = p[8];
  }
  d[0] = l;
  d[1] = v0[0]; d[2] = v0[1]; d[3] = v0[2]; d[4] = v0[3];
  d[5] = v1[0]; d[6] = v1[1]; d[7] = v1[2]; d[8] = v1[3];
  d[9] = rr;
}

// One block = one (batch, row): all 256 out-channels x 64 pixels.
// K-loop over input channels in steps of 32. Median taps come straight
// from global (no x LDS tile); only the med tile Bt goes through LDS.
__launch_bounds__(256, 4)
__global__ void fused_k(const float* __restrict__ x,
                        const unsigned short* __restrict__ wbf,
                        const float* __restrict__ bias,
                        float* __restrict__ out) {
  __shared__ unsigned short Bt[2][64][40];   // [buf][px][c], rows 80B (16B-aligned)
  __shared__ float BiasS[256];

  const int t   = threadIdx.x;
  const int blk = blockIdx.x;
  const int swz = ((blk & 7) << 8) | (blk >> 3);   // XCD-bijective swizzle (2048 = 8*256)
  const int b   = swz >> 6;
  const int r   = swz & 63;
  const int lane = t & 63;
  const int w    = t >> 6;       // wave 0..3
  const int g    = lane >> 4;    // lane group 0..3
  const int l15  = lane & 15;

  // median task: channel-local ci = t>>3 (0..31), pixel strip s = t&7 (8 px)
  const int ci  = t >> 3;
  const int s   = t & 7;
  const int px0 = s << 3;
  const int cw  = ci ^ ((s & 3) << 3);   // bank-deconflict: XOR channel-block by s&3

  BiasS[t] = bias[t];

  const float* xb = x + ((size_t)b << 20);   // b * 256*64*64
  const bool rT = (r >= 1), rB = (r <= 62);
  const bool hasL = (s > 0), hasR = (s < 7);

  f32x4 acc[4][4];
  #pragma unroll
  for (int m = 0; m < 4; ++m)
    #pragma unroll
    for (int n = 0; n < 4; ++n)
      acc[m][n] = (f32x4){0.f, 0.f, 0.f, 0.f};

  #pragma unroll 2
  for (int ks = 0; ks < 8; ++ks) {
    const int c0  = ks << 5;
    const int buf = ks & 1;

    // --- median of 8-px strip, channel c0+ci, from global ---
    const float* p = xb + ((size_t)(c0 + ci) << 12) + (r << 6) + px0;
    float R0[10], R1[10], R2[10];
    load_row(p - 64, rT,   hasL, hasR, R0);
    load_row(p,      true, hasL, hasR, R1);
    load_row(p + 64, rB,   hasL, hasR, R2);

    float mn[10], md[10], mx[10];
    #pragma unroll
    for (int j = 0; j < 10; ++j) {
      mn[j] = min3f(R0[j], R1[j], R2[j]);
      md[j] = med3f(R0[j], R1[j], R2[j]);
      mx[j] = max3f(R0[j], R1[j], R2[j]);
    }
    unsigned short mb[8];
    #pragma unroll
    for (int i = 0; i < 8; ++i) {
      float t0 = max3f(mn[i], mn[i+1], mn[i+2]);
      float t1 = med3f(md[i], md[i+1], md[i+2]);
      float t2 = min3f(mx[i], mx[i+1], mx[i+2]);
      mb[i] = f2bf(med3f(t0, t1, t2));
    }
    #pragma unroll
    for (int i = 0; i < 8; ++i)
      Bt[buf][px0 + i][cw] = mb[i];

    // --- W fragments straight from global (L2-hot, 128 KB total) ---
    bf16x8 a[4];
    #pragma unroll
    for (int m = 0; m < 4; ++m) {
      int o = (w << 6) + (m << 4) + l15;
      a[m] = __builtin_bit_cast(bf16x8, *(const u16x8*)(wbf + (o << 8) + c0 + (g << 3)));
    }

    __syncthreads();

    // --- B fragments (undo the XOR swizzle per 16-px row) + MFMA ---
    bf16x8 bb[4];
    #pragma unroll
    for (int n = 0; n < 4; ++n) {
      const int px = (n << 4) + l15;
      const int gc = (g ^ ((px >> 3) & 3)) << 3;
      bb[n] = __builtin_bit_cast(bf16x8, *(const u16x8*)&Bt[buf][px][gc]);
    }

    #pragma unroll
    for (int m = 0; m < 4; ++m)
      #pragma unroll
      for (int n = 0; n < 4; ++n)
        acc[m][n] = __builtin_amdgcn_mfma_f32_16x16x32_bf16(a[m], bb[n], acc[m][n], 0, 0, 0);
  }

  // --- epilogue: out = x + acc + bias ---
  #pragma unroll
  for (int m = 0; m < 4; ++m) {
    const int o = (w << 6) + (m << 4) + (g << 2);
    #pragma unroll
    for (int n = 0; n < 4; ++n) {
      const int px = (n << 4) + l15;
      const size_t base = ((((size_t)b << 8) + (size_t)o) << 12) + ((size_t)r << 6) + (size_t)px;
      #pragma unroll
      for (int q = 0; q < 4; ++q) {
        const size_t idx = base + ((size_t)q << 12);
        out[idx] = x[idx] + acc[m][n][q] + BiasS[o + q];
      }
    }
  }
}

extern "C" void kernel_launch(void* const* d_in, const int* in_sizes, int n_in,
                              void* d_out, int out_size, void* d_ws, size_t ws_size,
                              hipStream_t stream) {
  const float* x  = (const float*)d_in[0];
  const float* cw = (const float*)d_in[1];
  const float* cb = (const float*)d_in[2];
  float* out = (float*)d_out;
  unsigned short* wbf = (unsigned short*)d_ws;   // 128 KB

  hipLaunchKernelGGL(wconv_k, dim3(64), dim3(256), 0, stream, cw, wbf);
  hipLaunchKernelGGL(fused_k, dim3(2048), dim3(256), 0, stream, x, wbf, cb, out);
}

// Round 4
// 99.340 us; speedup vs baseline: 1.3780x; 1.1131x over previous
//
#include <hip/hip_runtime.h>

typedef float f32x4 __attribute__((ext_vector_type(4)));
typedef __bf16 bf16x8 __attribute__((ext_vector_type(8)));
typedef unsigned short u16x8 __attribute__((ext_vector_type(8)));

__device__ __forceinline__ unsigned short f2bf(float f) {
  union { float f; unsigned u; } v; v.f = f;
  unsigned r = v.u + 0x7FFFu + ((v.u >> 16) & 1u);
  return (unsigned short)(r >> 16);
}

__device__ __forceinline__ float min3f(float a, float b, float c) {
  return fminf(fminf(a, b), c);
}
__device__ __forceinline__ float max3f(float a, float b, float c) {
  return fmaxf(fmaxf(a, b), c);
}
__device__ __forceinline__ float med3f(float a, float b, float c) {
  return __builtin_amdgcn_fmed3f(a, b, c);
}

// conv_w fp32 [256][256] -> bf16 in MFMA-fragment-linear order:
// wbf[((ks*16 + ob)*64 + lane)*8 + j] = bf16(W[ob*16 + (lane&15)][ks*32 + (lane>>4)*8 + j])
__global__ void wconv_k(const float* __restrict__ w, unsigned short* __restrict__ wbf) {
  int idx  = blockIdx.x * 256 + threadIdx.x;   // 0..8191
  int lane = idx & 63;
  int ob   = (idx >> 6) & 15;
  int ks   = idx >> 10;                        // 0..7
  int o = (ob << 4) + (lane & 15);
  int c = (ks << 5) + ((lane >> 4) << 3);
  const float* src = w + (o << 8) + c;
  f32x4 v0 = *(const f32x4*)src;
  f32x4 v1 = *(const f32x4*)(src + 4);
  u16x8 ov;
  ov[0] = f2bf(v0[0]); ov[1] = f2bf(v0[1]); ov[2] = f2bf(v0[2]); ov[3] = f2bf(v0[3]);
  ov[4] = f2bf(v1[0]); ov[5] = f2bf(v1[1]); ov[6] = f2bf(v1[2]); ov[7] = f2bf(v1[3]);
  *(u16x8*)(wbf + (idx << 3)) = ov;
}

// One block = one (batch, row): all 256 out-channels x 64 pixels.
// K-loop (fully unrolled) over input channels in steps of 32, with
// 2-step-deep register prefetch of the x strips and coalesced W fragments.
__launch_bounds__(256, 2)
__global__ void fused_k(const float* __restrict__ x,
                        const unsigned short* __restrict__ wbf,
                        const float* __restrict__ bias,
                        float* __restrict__ out) {
  __shared__ unsigned short Bt[2][64][40];   // [buf][px][c-swizzled], rows 80B
  __shared__ float BiasS[256];

  const int t   = threadIdx.x;
  const int blk = blockIdx.x;
  const int swz = ((blk & 7) << 8) | (blk >> 3);   // XCD-bijective swizzle (2048 = 8*256)
  const int b   = swz >> 6;
  const int r   = swz & 63;
  const int lane = t & 63;
  const int w    = t >> 6;       // wave 0..3
  const int g    = lane >> 4;    // lane group 0..3
  const int l15  = lane & 15;

  // median task: channel-local ci = t>>3 (0..31), pixel strip s = t&7 (8 px)
  const int ci  = t >> 3;
  const int s   = t & 7;
  const int px0 = s << 3;
  const int cw  = ci ^ ((s & 3) << 3);   // bank-deconflict: XOR channel-block by s&3

  BiasS[t] = bias[t];

  const float* xb = x + ((size_t)b << 20);   // b * 256*64*64
  const bool rT = (r >= 1), rB = (r <= 62);
  const bool hasL = (s > 0), hasR = (s < 7);
  const float* pbase = xb + ((size_t)ci << 12) + (r << 6) + px0;  // + step*32*4096

  f32x4 acc[4][4];
  #pragma unroll
  for (int m = 0; m < 4; ++m)
    #pragma unroll
    for (int n = 0; n < 4; ++n)
      acc[m][n] = (f32x4){0.f, 0.f, 0.f, 0.f};

  // rolling 3-buffer register prefetch of the aligned strip (6 x f32x4 per step)
  f32x4 pf[3][6];
  #pragma unroll
  for (int q = 0; q < 2; ++q) {
    const float* p = pbase + ((size_t)(q << 5) << 12);
    pf[q][0] = pf[q][1] = pf[q][4] = pf[q][5] = (f32x4){0.f, 0.f, 0.f, 0.f};
    if (rT) { pf[q][0] = *(const f32x4*)(p - 64); pf[q][1] = *(const f32x4*)(p - 60); }
    pf[q][2] = *(const f32x4*)p;       pf[q][3] = *(const f32x4*)(p + 4);
    if (rB) { pf[q][4] = *(const f32x4*)(p + 64); pf[q][5] = *(const f32x4*)(p + 68); }
  }

  #pragma unroll
  for (int ks = 0; ks < 8; ++ks) {
    const int buf = ks & 1;

    // --- A fragments: fragment-linear W, fully coalesced (lane*16B) ---
    bf16x8 a[4];
    #pragma unroll
    for (int m = 0; m < 4; ++m) {
      const int fidx = (((ks << 4) + (w << 2) + m) << 6) + lane;
      a[m] = __builtin_bit_cast(bf16x8, *(const u16x8*)(wbf + ((size_t)fidx << 3)));
    }

    // --- prefetch step ks+2's aligned strip ---
    if (ks < 6) {
      const int q2 = (ks + 2) % 3;
      const float* p = pbase + ((size_t)((ks + 2) << 5) << 12);
      pf[q2][0] = pf[q2][1] = pf[q2][4] = pf[q2][5] = (f32x4){0.f, 0.f, 0.f, 0.f};
      if (rT) { pf[q2][0] = *(const f32x4*)(p - 64); pf[q2][1] = *(const f32x4*)(p - 60); }
      pf[q2][2] = *(const f32x4*)p;       pf[q2][3] = *(const f32x4*)(p + 4);
      if (rB) { pf[q2][4] = *(const f32x4*)(p + 64); pf[q2][5] = *(const f32x4*)(p + 68); }
    }

    // --- edge scalars for current step (lines are L1/L2-hot) ---
    const float* pc = pbase + ((size_t)(ks << 5) << 12);
    float eTL = 0.f, eTR = 0.f, eML = 0.f, eMR = 0.f, eBL = 0.f, eBR = 0.f;
    if (rT && hasL) eTL = pc[-65];
    if (rT && hasR) eTR = pc[-56];
    if (hasL)       eML = pc[-1];
    if (hasR)       eMR = pc[8];
    if (rB && hasL) eBL = pc[63];
    if (rB && hasR) eBR = pc[72];

    // --- median of the 8-px strip from registers ---
    const f32x4* C = pf[ks % 3];
    float R0[10] = { eTL, C[0][0],C[0][1],C[0][2],C[0][3], C[1][0],C[1][1],C[1][2],C[1][3], eTR };
    float R1[10] = { eML, C[2][0],C[2][1],C[2][2],C[2][3], C[3][0],C[3][1],C[3][2],C[3][3], eMR };
    float R2[10] = { eBL, C[4][0],C[4][1],C[4][2],C[4][3], C[5][0],C[5][1],C[5][2],C[5][3], eBR };

    float mn[10], md[10], mx[10];
    #pragma unroll
    for (int j = 0; j < 10; ++j) {
      mn[j] = min3f(R0[j], R1[j], R2[j]);
      md[j] = med3f(R0[j], R1[j], R2[j]);
      mx[j] = max3f(R0[j], R1[j], R2[j]);
    }
    unsigned short mb[8];
    #pragma unroll
    for (int i = 0; i < 8; ++i) {
      float t0 = max3f(mn[i], mn[i+1], mn[i+2]);
      float t1 = med3f(md[i], md[i+1], md[i+2]);
      float t2 = min3f(mx[i], mx[i+1], mx[i+2]);
      mb[i] = f2bf(med3f(t0, t1, t2));
    }
    #pragma unroll
    for (int i = 0; i < 8; ++i)
      Bt[buf][px0 + i][cw] = mb[i];

    __syncthreads();

    // --- B fragments (undo the XOR swizzle per 16-px row) + MFMA ---
    bf16x8 bb[4];
    #pragma unroll
    for (int n = 0; n < 4; ++n) {
      const int px = (n << 4) + l15;
      const int gc = (g ^ ((px >> 3) & 3)) << 3;
      bb[n] = __builtin_bit_cast(bf16x8, *(const u16x8*)&Bt[buf][px][gc]);
    }

    #pragma unroll
    for (int m = 0; m < 4; ++m)
      #pragma unroll
      for (int n = 0; n < 4; ++n)
        acc[m][n] = __builtin_amdgcn_mfma_f32_16x16x32_bf16(a[m], bb[n], acc[m][n], 0, 0, 0);
  }

  // --- epilogue: out = x + acc + bias ---
  #pragma unroll
  for (int m = 0; m < 4; ++m) {
    const int o = (w << 6) + (m << 4) + (g << 2);
    #pragma unroll
    for (int n = 0; n < 4; ++n) {
      const int px = (n << 4) + l15;
      const size_t base = ((((size_t)b << 8) + (size_t)o) << 12) + ((size_t)r << 6) + (size_t)px;
      #pragma unroll
      for (int q = 0; q < 4; ++q) {
        const size_t idx = base + ((size_t)q << 12);
        out[idx] = x[idx] + acc[m][n][q] + BiasS[o + q];
      }
    }
  }
}

extern "C" void kernel_launch(void* const* d_in, const int* in_sizes, int n_in,
                              void* d_out, int out_size, void* d_ws, size_t ws_size,
                              hipStream_t stream) {
  const float* x  = (const float*)d_in[0];
  const float* cw = (const float*)d_in[1];
  const float* cb = (const float*)d_in[2];
  float* out = (float*)d_out;
  unsigned short* wbf = (unsigned short*)d_ws;   // 128 KB fragment-linear W

  hipLaunchKernelGGL(wconv_k, dim3(32), dim3(256), 0, stream, cw, wbf);
  hipLaunchKernelGGL(fused_k, dim3(2048), dim3(256), 0, stream, x, wbf, cb, out);
}

// Round 5
// 76.740 us; speedup vs baseline: 1.7838x; 1.2945x over previous
//
#include <hip/hip_runtime.h>

typedef float f32x4 __attribute__((ext_vector_type(4)));
typedef __bf16 bf16x8 __attribute__((ext_vector_type(8)));
typedef unsigned short u16x8 __attribute__((ext_vector_type(8)));

__device__ __forceinline__ unsigned short f2bf(float f) {
  union { float f; unsigned u; } v; v.f = f;
  unsigned r = v.u + 0x7FFFu + ((v.u >> 16) & 1u);
  return (unsigned short)(r >> 16);
}

__device__ __forceinline__ float min3f(float a, float b, float c) {
  return fminf(fminf(a, b), c);
}
__device__ __forceinline__ float max3f(float a, float b, float c) {
  return fmaxf(fmaxf(a, b), c);
}
__device__ __forceinline__ float med3f(float a, float b, float c) {
  return __builtin_amdgcn_fmed3f(a, b, c);
}

// conv_w fp32 [256][256] -> bf16 in MFMA-fragment-linear order:
// wbf[((ks*16 + ob)*64 + lane)*8 + j] = bf16(W[ob*16 + (lane&15)][ks*32 + (lane>>4)*8 + j])
__global__ void wconv_k(const float* __restrict__ w, unsigned short* __restrict__ wbf) {
  int idx  = blockIdx.x * 256 + threadIdx.x;   // 0..8191
  int lane = idx & 63;
  int ob   = (idx >> 6) & 15;
  int ks   = idx >> 10;                        // 0..7
  int o = (ob << 4) + (lane & 15);
  int c = (ks << 5) + ((lane >> 4) << 3);
  const float* src = w + (o << 8) + c;
  f32x4 v0 = *(const f32x4*)src;
  f32x4 v1 = *(const f32x4*)(src + 4);
  u16x8 ov;
  ov[0] = f2bf(v0[0]); ov[1] = f2bf(v0[1]); ov[2] = f2bf(v0[2]); ov[3] = f2bf(v0[3]);
  ov[4] = f2bf(v1[0]); ov[5] = f2bf(v1[1]); ov[6] = f2bf(v1[2]); ov[7] = f2bf(v1[3]);
  *(u16x8*)(wbf + (idx << 3)) = ov;
}

// One block = one (batch, row). K-loop fully unrolled, medians software-
// pipelined one step ahead of the MFMA; halo via lane shuffles (no edge
// loads); 3-slot rotating register prefetch of the aligned x strips.
__launch_bounds__(256, 2)
__global__ void fused_k(const float* __restrict__ x,
                        const unsigned short* __restrict__ wbf,
                        const float* __restrict__ bias,
                        float* __restrict__ out) {
  __shared__ unsigned short Bt[2][64][40];   // [buf][px][c-swizzled], rows 80B
  __shared__ float BiasS[256];

  const int t   = threadIdx.x;
  const int blk = blockIdx.x;
  const int swz = ((blk & 7) << 8) | (blk >> 3);   // XCD-bijective swizzle (2048 = 8*256)
  const int b   = swz >> 6;
  const int r   = swz & 63;
  const int lane = t & 63;
  const int w    = t >> 6;       // wave 0..3
  const int g    = lane >> 4;    // lane group 0..3
  const int l15  = lane & 15;

  // median task: channel-local ci = t>>3 (0..31), pixel strip s = t&7 (8 px)
  const int ci  = t >> 3;
  const int s   = t & 7;
  const int px0 = s << 3;
  const int cw  = ci ^ ((s & 3) << 3);   // bank-deconflict: XOR channel-block by s&3

  BiasS[t] = bias[t];

  const float* xb = x + ((size_t)b << 20);   // b * 256*64*64
  const bool rT = (r >= 1), rB = (r <= 62);
  const bool hasL = (s > 0), hasR = (s < 7);
  const float* pbase = xb + ((size_t)ci << 12) + (r << 6) + px0;  // + step*32*4096

  f32x4 acc[4][4];
  #pragma unroll
  for (int m = 0; m < 4; ++m)
    #pragma unroll
    for (int n = 0; n < 4; ++n)
      acc[m][n] = (f32x4){0.f, 0.f, 0.f, 0.f};

  f32x4 pf[3][6];   // rotating prefetch: 3 rows x 2 f32x4 of the 8-px strip

  auto load_strip = [&](int step, f32x4* dst) {
    const float* p = pbase + ((size_t)(step << 5) << 12);
    dst[0] = dst[1] = dst[4] = dst[5] = (f32x4){0.f, 0.f, 0.f, 0.f};
    if (rT) { dst[0] = *(const f32x4*)(p - 64); dst[1] = *(const f32x4*)(p - 60); }
    dst[2] = *(const f32x4*)p;       dst[3] = *(const f32x4*)(p + 4);
    if (rB) { dst[4] = *(const f32x4*)(p + 64); dst[5] = *(const f32x4*)(p + 68); }
  };

  // median of the 8-px strip; halo from lane+-1 registers via shuffle
  auto median_store = [&](const f32x4* C, int buf) {
    float tl = __shfl_up(C[1][3], 1);
    float ml = __shfl_up(C[3][3], 1);
    float bl = __shfl_up(C[5][3], 1);
    float tr = __shfl_down(C[0][0], 1);
    float mr = __shfl_down(C[2][0], 1);
    float br = __shfl_down(C[4][0], 1);
    float R0[10], R1[10], R2[10];
    R0[0] = hasL ? tl : 0.f;  R1[0] = hasL ? ml : 0.f;  R2[0] = hasL ? bl : 0.f;
    R0[9] = hasR ? tr : 0.f;  R1[9] = hasR ? mr : 0.f;  R2[9] = hasR ? br : 0.f;
    #pragma unroll
    for (int j = 0; j < 4; ++j) {
      R0[1 + j] = C[0][j];  R0[5 + j] = C[1][j];
      R1[1 + j] = C[2][j];  R1[5 + j] = C[3][j];
      R2[1 + j] = C[4][j];  R2[5 + j] = C[5][j];
    }
    float mn[10], md[10], mx[10];
    #pragma unroll
    for (int j = 0; j < 10; ++j) {
      mn[j] = min3f(R0[j], R1[j], R2[j]);
      md[j] = med3f(R0[j], R1[j], R2[j]);
      mx[j] = max3f(R0[j], R1[j], R2[j]);
    }
    #pragma unroll
    for (int i = 0; i < 8; ++i) {
      float t0 = max3f(mn[i], mn[i+1], mn[i+2]);
      float t1 = med3f(md[i], md[i+1], md[i+2]);
      float t2 = min3f(mx[i], mx[i+1], mx[i+2]);
      Bt[buf][px0 + i][cw] = f2bf(med3f(t0, t1, t2));
    }
  };

  // prologue: 3 strips in flight, median(0) published
  load_strip(0, pf[0]);
  load_strip(1, pf[1]);
  load_strip(2, pf[2]);
  median_store(pf[0], 0);
  __syncthreads();

  #pragma unroll
  for (int ks = 0; ks < 8; ++ks) {
    // --- B fragments of step ks (published at previous barrier) ---
    bf16x8 bb[4];
    #pragma unroll
    for (int n = 0; n < 4; ++n) {
      const int px = (n << 4) + l15;
      const int gc = (g ^ ((px >> 3) & 3)) << 3;
      bb[n] = __builtin_bit_cast(bf16x8, *(const u16x8*)&Bt[ks & 1][px][gc]);
    }
    // --- A fragments: fragment-linear W, fully coalesced ---
    bf16x8 a[4];
    #pragma unroll
    for (int m = 0; m < 4; ++m) {
      const int fidx = (((ks << 4) + (w << 2) + m) << 6) + lane;
      a[m] = __builtin_bit_cast(bf16x8, *(const u16x8*)(wbf + ((size_t)fidx << 3)));
    }
    // --- prefetch step ks+3 into the slot freed last step ---
    if (ks <= 4) load_strip(ks + 3, pf[ks % 3]);
    // --- median for step ks+1 (overlaps this step's MFMA region) ---
    if (ks < 7) median_store(pf[(ks + 1) % 3], (ks + 1) & 1);

    #pragma unroll
    for (int m = 0; m < 4; ++m)
      #pragma unroll
      for (int n = 0; n < 4; ++n)
        acc[m][n] = __builtin_amdgcn_mfma_f32_16x16x32_bf16(a[m], bb[n], acc[m][n], 0, 0, 0);

    if (ks < 7) __syncthreads();
  }

  // --- epilogue: out = x + acc + bias ---
  #pragma unroll
  for (int m = 0; m < 4; ++m) {
    const int o = (w << 6) + (m << 4) + (g << 2);
    #pragma unroll
    for (int n = 0; n < 4; ++n) {
      const int px = (n << 4) + l15;
      const size_t base = ((((size_t)b << 8) + (size_t)o) << 12) + ((size_t)r << 6) + (size_t)px;
      #pragma unroll
      for (int q = 0; q < 4; ++q) {
        const size_t idx = base + ((size_t)q << 12);
        out[idx] = x[idx] + acc[m][n][q] + BiasS[o + q];
      }
    }
  }
}

extern "C" void kernel_launch(void* const* d_in, const int* in_sizes, int n_in,
                              void* d_out, int out_size, void* d_ws, size_t ws_size,
                              hipStream_t stream) {
  const float* x  = (const float*)d_in[0];
  const float* cw = (const float*)d_in[1];
  const float* cb = (const float*)d_in[2];
  float* out = (float*)d_out;
  unsigned short* wbf = (unsigned short*)d_ws;   // 128 KB fragment-linear W

  hipLaunchKernelGGL(wconv_k, dim3(32), dim3(256), 0, stream, cw, wbf);
  hipLaunchKernelGGL(fused_k, dim3(2048), dim3(256), 0, stream, x, wbf, cb, out);
}

// Round 6
// 74.090 us; speedup vs baseline: 1.8476x; 1.0358x over previous
//
#include <hip/hip_runtime.h>

typedef float f32x4 __attribute__((ext_vector_type(4)));
typedef __bf16 bf16x8 __attribute__((ext_vector_type(8)));
typedef unsigned short u16x8 __attribute__((ext_vector_type(8)));

__device__ __forceinline__ unsigned short f2bf(float f) {
  union { float f; unsigned u; } v; v.f = f;
  unsigned r = v.u + 0x7FFFu + ((v.u >> 16) & 1u);
  return (unsigned short)(r >> 16);
}

__device__ __forceinline__ float min3f(float a, float b, float c) {
  return fminf(fminf(a, b), c);
}
__device__ __forceinline__ float max3f(float a, float b, float c) {
  return fmaxf(fmaxf(a, b), c);
}
__device__ __forceinline__ float med3f(float a, float b, float c) {
  return __builtin_amdgcn_fmed3f(a, b, c);
}

// async global->LDS, 16B per lane, LDS dest = wave-uniform base + lane*16
__device__ __forceinline__ void gload_lds16(const void* g, void* l) {
  __builtin_amdgcn_global_load_lds(
      (const __attribute__((address_space(1))) void*)g,
      (__attribute__((address_space(3))) void*)l, 16, 0, 0);
}

// conv_w fp32 [256][256] -> bf16 in MFMA-fragment-linear order:
// wbf[((ks*16 + ob)*64 + lane)*8 + j] = bf16(W[ob*16 + (lane&15)][ks*32 + (lane>>4)*8 + j])
__global__ void wconv_k(const float* __restrict__ w, unsigned short* __restrict__ wbf) {
  int idx  = blockIdx.x * 256 + threadIdx.x;   // 0..8191
  int lane = idx & 63;
  int ob   = (idx >> 6) & 15;
  int ks   = idx >> 10;                        // 0..7
  int o = (ob << 4) + (lane & 15);
  int c = (ks << 5) + ((lane >> 4) << 3);
  const float* src = w + (o << 8) + c;
  f32x4 v0 = *(const f32x4*)src;
  f32x4 v1 = *(const f32x4*)(src + 4);
  u16x8 ov;
  ov[0] = f2bf(v0[0]); ov[1] = f2bf(v0[1]); ov[2] = f2bf(v0[2]); ov[3] = f2bf(v0[3]);
  ov[4] = f2bf(v1[0]); ov[5] = f2bf(v1[1]); ov[6] = f2bf(v1[2]); ov[7] = f2bf(v1[3]);
  *(u16x8*)(wbf + (idx << 3)) = ov;
}

// One block = one (batch, row). x tile staged via global_load_lds (async,
// source-pre-swizzled for conflict-free reads); medians from LDS; med tile
// Bt -> MFMA. Single-buffered Xs, 2 barriers/step, 3 blocks/CU.
__launch_bounds__(256, 3)
__global__ void fused_k(const float* __restrict__ x,
                        const unsigned short* __restrict__ wbf,
                        const float* __restrict__ bias,
                        float* __restrict__ out) {
  __shared__ float Xs[96][64];               // 24 KB: row = ci*3+dr, px-block swizzled
  __shared__ unsigned short Bt[64][40];      //  5 KB: med tile [px][c-swizzled]
  __shared__ float BiasS[256];

  const int t   = threadIdx.x;
  const int blk = blockIdx.x;
  const int swz = ((blk & 7) << 8) | (blk >> 3);   // XCD-bijective (2048 = 8*256)
  const int b   = swz >> 6;
  const int r   = swz & 63;
  const int lane = t & 63;
  const int w    = t >> 6;       // wave 0..3
  const int g    = lane >> 4;    // lane group 0..3
  const int l15  = lane & 15;

  // median task: channel ci = t>>3 (0..31), pixel strip s = t&7 (8 px)
  const int ci  = t >> 3;
  const int s   = t & 7;
  const int px0 = s << 3;
  const int cw  = ci ^ ((s & 3) << 3);   // Bt bank-deconflict swizzle
  const bool rT = (r >= 1), rB = (r <= 62);
  const bool hasL = (s > 0), hasR = (s < 7);

  BiasS[t] = bias[t];

  const float* xb = x + ((size_t)b << 20);   // b * 256*64*64

  // --- staging source byte-offsets (wave w stages rows w*24 .. w*24+23) ---
  // issue p covers rows w*24+p*4+(lane>>4); lane writes LDS block bL=lane&15,
  // sourcing global block bG = bL ^ (ci&7)  (read-side inverse applied below)
  unsigned soff[6];
  #pragma unroll
  for (int p = 0; p < 6; ++p) {
    int row = w * 24 + (p << 2) + (lane >> 4);
    int cip = (row * 171) >> 9;            // row / 3 (exact for row < 96)
    int drp = row - cip * 3;
    int gr  = r + drp - 1;
    gr = gr < 0 ? 0 : (gr > 63 ? 63 : gr); // clamp; zeroed in VALU at median time
    int bG  = (lane & 15) ^ (cip & 7);
    soff[p] = ((unsigned)cip << 14) + ((unsigned)gr << 8) + ((unsigned)bG << 4);
  }

  // prologue: stage step 0
  #pragma unroll
  for (int p = 0; p < 6; ++p)
    gload_lds16((const char*)xb + soff[p], &Xs[w * 24 + (p << 2)][0]);

  f32x4 acc[4][4];
  #pragma unroll
  for (int m = 0; m < 4; ++m)
    #pragma unroll
    for (int n = 0; n < 4; ++n)
      acc[m][n] = (f32x4){0.f, 0.f, 0.f, 0.f};

  // loop-invariant LDS read offsets (swizzled block indices)
  const int ri0 = ci * 3;
  const int sig = ci & 7;
  const int bAi = ((s << 1)) ^ sig;
  const int bBi = ((s << 1) | 1) ^ sig;
  const int bLi = (((s << 1) - 1) & 15) ^ sig;
  const int bRi = (((s << 1) + 2) & 15) ^ sig;

  __syncthreads();   // prologue loads drained (vmcnt0) + all waves ready

  #pragma unroll
  for (int ks = 0; ks < 8; ++ks) {
    // --- A fragments (L2-hot; consumed by MFMA after barrier 1) ---
    bf16x8 a[4];
    #pragma unroll
    for (int m = 0; m < 4; ++m) {
      const int fidx = (((ks << 4) + (w << 2) + m) << 6) + lane;
      a[m] = __builtin_bit_cast(bf16x8, *(const u16x8*)(wbf + ((size_t)fidx << 3)));
    }

    // --- median of the 8-px strip from Xs ---
    float R[3][10];
    #pragma unroll
    for (int dr = 0; dr < 3; ++dr) {
      const float* rp = &Xs[ri0 + dr][0];
      f32x4 va = *(const f32x4*)(rp + (bAi << 2));
      f32x4 vb = *(const f32x4*)(rp + (bBi << 2));
      R[dr][0] = hasL ? rp[(bLi << 2) + 3] : 0.f;
      R[dr][9] = hasR ? rp[(bRi << 2)]     : 0.f;
      #pragma unroll
      for (int j = 0; j < 4; ++j) { R[dr][1 + j] = va[j]; R[dr][5 + j] = vb[j]; }
    }
    if (!rT) {                     // uniform per block (r==0 only)
      #pragma unroll
      for (int j = 0; j < 10; ++j) R[0][j] = 0.f;
    }
    if (!rB) {                     // uniform per block (r==63 only)
      #pragma unroll
      for (int j = 0; j < 10; ++j) R[2][j] = 0.f;
    }

    float mn[10], md[10], mx[10];
    #pragma unroll
    for (int j = 0; j < 10; ++j) {
      mn[j] = min3f(R[0][j], R[1][j], R[2][j]);
      md[j] = med3f(R[0][j], R[1][j], R[2][j]);
      mx[j] = max3f(R[0][j], R[1][j], R[2][j]);
    }
    #pragma unroll
    for (int i = 0; i < 8; ++i) {
      float t0 = max3f(mn[i], mn[i+1], mn[i+2]);
      float t1 = med3f(md[i], md[i+1], md[i+2]);
      float t2 = min3f(mx[i], mx[i+1], mx[i+2]);
      Bt[px0 + i][cw] = f2bf(med3f(t0, t1, t2));
    }

    __syncthreads();   // barrier 1: Bt published, Xs fully consumed

    // --- stage next step's x tile (in flight across MFMA, drained at barrier 2) ---
    if (ks < 7) {
      const unsigned kso = (unsigned)(ks + 1) << 19;   // 32 ch * 4096 px * 4 B
      #pragma unroll
      for (int p = 0; p < 6; ++p)
        gload_lds16((const char*)xb + (soff[p] + kso), &Xs[w * 24 + (p << 2)][0]);
    }

    // --- B fragments (undo Bt swizzle per 16-px row) + MFMA ---
    bf16x8 bb[4];
    #pragma unroll
    for (int n = 0; n < 4; ++n) {
      const int px = (n << 4) + l15;
      const int gc = (g ^ ((px >> 3) & 3)) << 3;
      bb[n] = __builtin_bit_cast(bf16x8, *(const u16x8*)&Bt[px][gc]);
    }
    #pragma unroll
    for (int m = 0; m < 4; ++m)
      #pragma unroll
      for (int n = 0; n < 4; ++n)
        acc[m][n] = __builtin_amdgcn_mfma_f32_16x16x32_bf16(a[m], bb[n], acc[m][n], 0, 0, 0);

    if (ks < 7) __syncthreads();   // barrier 2: staged loads landed before reads
  }

  // --- epilogue: out = x + acc + bias ---
  #pragma unroll
  for (int m = 0; m < 4; ++m) {
    const int o = (w << 6) + (m << 4) + (g << 2);
    #pragma unroll
    for (int n = 0; n < 4; ++n) {
      const int px = (n << 4) + l15;
      const size_t base = ((((size_t)b << 8) + (size_t)o) << 12) + ((size_t)r << 6) + (size_t)px;
      #pragma unroll
      for (int q = 0; q < 4; ++q) {
        const size_t idx = base + ((size_t)q << 12);
        out[idx] = x[idx] + acc[m][n][q] + BiasS[o + q];
      }
    }
  }
}

extern "C" void kernel_launch(void* const* d_in, const int* in_sizes, int n_in,
                              void* d_out, int out_size, void* d_ws, size_t ws_size,
                              hipStream_t stream) {
  const float* x  = (const float*)d_in[0];
  const float* cw = (const float*)d_in[1];
  const float* cb = (const float*)d_in[2];
  float* out = (float*)d_out;
  unsigned short* wbf = (unsigned short*)d_ws;   // 128 KB fragment-linear W

  hipLaunchKernelGGL(wconv_k, dim3(32), dim3(256), 0, stream, cw, wbf);
  hipLaunchKernelGGL(fused_k, dim3(2048), dim3(256), 0, stream, x, wbf, cb, out);
}